// Round 9
// baseline (208.608 us; speedup 1.0000x reference)
//
#include <hip/hip_runtime.h>

#define Bb 2
#define Ss 2048
#define Dd 1024
#define Hh 16
#define HDd 64
#define BS (Bb * Ss)

typedef __attribute__((ext_vector_type(8))) __bf16 bf16x8;
typedef __attribute__((ext_vector_type(8))) unsigned short u16x8;
typedef __attribute__((ext_vector_type(4))) float f32x4;

__device__ __forceinline__ unsigned short f2bf(float f) {
  union { float f; unsigned u; } v; v.f = f;
  unsigned r = v.u + 0x7fffu + ((v.u >> 16) & 1u);
  return (unsigned short)(r >> 16);
}
__device__ __forceinline__ unsigned short f2bf_fast(float f) {  // RN, no tie fix
  union { float f; unsigned u; } v; v.f = f;
  return (unsigned short)((v.u + 0x8000u) >> 16);
}

// async global->LDS, 16B per lane; LDS dest = wave-uniform base + lane*16.
// NOTE (R8 lesson): keep <=4 of these in flight per thread — the R8 kernel
// with 8 outstanding raced under graph replay.
__device__ __forceinline__ void gl_lds16(const void* g, void* l) {
  __builtin_amdgcn_global_load_lds(
      (const __attribute__((address_space(1))) void*)g,
      (__attribute__((address_space(3))) void*)l, 16, 0, 0);
}

// -------- cast fp32 -> bf16 (x, wq|wk|wv stacked, wo) + RoPE cos/sin table --
__global__ __launch_bounds__(256) void cast_all(
    const float4* __restrict__ x, const float4* __restrict__ wq,
    const float4* __restrict__ wk, const float4* __restrict__ wv,
    const float4* __restrict__ wo, ushort4* __restrict__ xb,
    ushort4* __restrict__ wqkvb, ushort4* __restrict__ wob,
    float* __restrict__ ct, float* __restrict__ st) {
  int i = blockIdx.x * 256 + threadIdx.x;
  const int NX4 = BS * Dd / 4;   // 1M
  const int NW4 = Dd * Dd / 4;   // 256K
  const float4* src;
  ushort4* dst;
  int idx;
  if (i < NX4) { src = x; dst = xb; idx = i; }
  else if ((i -= NX4) < NW4) { src = wq; dst = wqkvb; idx = i; }
  else if ((i -= NW4) < NW4) { src = wk; dst = wqkvb + NW4; idx = i; }
  else if ((i -= NW4) < NW4) { src = wv; dst = wqkvb + 2 * NW4; idx = i; }
  else if ((i -= NW4) < NW4) { src = wo; dst = wob; idx = i; }
  else if ((i -= NW4) < Ss * 32) {  // RoPE table: i = s*32 + j
    int s = i >> 5, jj = i & 31;
    float freq = __powf(10000.0f, -(float)jj * (1.0f / 32.0f));
    float cs, sn;
    sincosf((float)s * freq, &sn, &cs);
    ct[i] = cs; st[i] = sn;
    return;
  } else return;
  float4 v = src[idx];
  ushort4 o;
  o.x = f2bf(v.x); o.y = f2bf(v.y); o.z = f2bf(v.z); o.w = f2bf(v.w);
  dst[idx] = o;
}

// -------- fused QKV GEMM + QK-RMSNorm + RoPE + layout, dbuf K-loop ----------
// C[m][n] = sum_k A[m][k]*Bw[n][k], M=4096 N=3072 K=1024, 128x128 tile, BK=32.
// R9: flash-style LDS double-buffer — one barrier per K-iter; stage buf
// (it+1)&1 right after the barrier, compute from buf it&1. Compute (~900 cyc)
// hides the staging loads' latency; the next barrier's vmcnt drain finds them
// landed. Max 4 gl_lds16 in flight per thread.
// Epilogue per wave = one head (64 rows x 64 cols): type 0=Q (norm+rope,
// x0.125*log2e), 1=K (norm+rope), 2=V (transpose store [B,H,HD,S]).
__global__ __launch_bounds__(256) void gemm_qkv(
    const unsigned short* __restrict__ A, const unsigned short* __restrict__ Bw,
    const float* __restrict__ qw, const float* __restrict__ kw,
    const float* __restrict__ ct, const float* __restrict__ st,
    unsigned short* __restrict__ Qb, unsigned short* __restrict__ Kb,
    unsigned short* __restrict__ Vt) {
  __shared__ __align__(16) unsigned short As[2][128 * 32];  // 8 KB each
  __shared__ __align__(16) unsigned short Bs[2][128 * 32];
  const int K = Dd, tid = threadIdx.x;
  const int lane = tid & 63;
  const int quad = lane >> 4;
  const int l16 = lane & 15;
  const int wave = tid >> 6;
  const int wm = (wave >> 1) * 64;
  const int wn = (wave & 1) * 64;
  const int tile_m = blockIdx.y * 128;
  const int tile_n = blockIdx.x * 128;

  const int off0 = tid * 16;
  const int off1 = 4096 + tid * 16;
  const int r0 = tid >> 2, r1 = r0 + 64;
  const int sch = (((tid & 3) ^ ((tid >> 3) & 3)) << 3);  // swizzled src elem
  const int xg = ((quad ^ ((l16 >> 1) & 3)) << 3);        // swizzled read elem

  const unsigned short* Ag0 = A + (size_t)(tile_m + r0) * K + sch;
  const unsigned short* Ag1 = A + (size_t)(tile_m + r1) * K + sch;
  const unsigned short* Bg0 = Bw + (size_t)(tile_n + r0) * K + sch;
  const unsigned short* Bg1 = Bw + (size_t)(tile_n + r1) * K + sch;

  f32x4 zero = {0.f, 0.f, 0.f, 0.f};
  f32x4 acc[4][4];
#pragma unroll
  for (int mi = 0; mi < 4; ++mi)
#pragma unroll
    for (int ni = 0; ni < 4; ++ni) acc[mi][ni] = zero;

  // prologue: stage iter 0 into buf 0
  gl_lds16(Ag0, (char*)As[0] + off0);
  gl_lds16(Ag1, (char*)As[0] + off1);
  gl_lds16(Bg0, (char*)Bs[0] + off0);
  gl_lds16(Bg1, (char*)Bs[0] + off1);

  const int NIT = 32;  // K/32
  for (int it = 0; it < NIT; ++it) {
    __syncthreads();  // buf[it&1] staged (drains prefetch DMA)
    if (it + 1 < NIT) {
      const int k1 = (it + 1) * 32, bn = (it + 1) & 1;
      gl_lds16(Ag0 + k1, (char*)As[bn] + off0);
      gl_lds16(Ag1 + k1, (char*)As[bn] + off1);
      gl_lds16(Bg0 + k1, (char*)Bs[bn] + off0);
      gl_lds16(Bg1 + k1, (char*)Bs[bn] + off1);
    }
    const unsigned short* Asb = As[it & 1];
    const unsigned short* Bsb = Bs[it & 1];
    bf16x8 af[4], bfv[4];
#pragma unroll
    for (int mi = 0; mi < 4; ++mi)
      af[mi] = *(const bf16x8*)&Asb[(wm + mi * 16 + l16) * 32 + xg];
#pragma unroll
    for (int ni = 0; ni < 4; ++ni)
      bfv[ni] = *(const bf16x8*)&Bsb[(wn + ni * 16 + l16) * 32 + xg];
#pragma unroll
    for (int mi = 0; mi < 4; ++mi)
#pragma unroll
      for (int ni = 0; ni < 4; ++ni)
        acc[mi][ni] = __builtin_amdgcn_mfma_f32_16x16x32_bf16(
            af[mi], bfv[ni], acc[mi][ni], 0, 0, 0);
  }

  // ---- fused epilogue. C-layout: row = wm+mi*16+quad*4+r, col = wn+ni*16+l16
  const int type = blockIdx.x >> 3;                    // 0=Q,1=K,2=V
  const int h = (((blockIdx.x & 7) << 7) + wn) >> 6;   // head index
  const int bb = tile_m >> 11;
  const size_t bh = (size_t)bb * Hh + h;

  if (type == 2) {  // V: transpose store Vt[bh][d][s], pack 4 tokens
#pragma unroll
    for (int mi = 0; mi < 4; ++mi) {
      int s0 = (tile_m + wm + mi * 16 + quad * 4) & (Ss - 1);
#pragma unroll
      for (int ni = 0; ni < 4; ++ni) {
        int d = ni * 16 + l16;
        ushort4 pv;
        pv.x = f2bf(acc[mi][ni][0]);
        pv.y = f2bf(acc[mi][ni][1]);
        pv.z = f2bf(acc[mi][ni][2]);
        pv.w = f2bf(acc[mi][ni][3]);
        *(ushort4*)&Vt[(bh * HDd + d) * Ss + s0] = pv;
      }
    }
  } else {
    const float* wnp = type ? kw : qw;
    unsigned short* Ob = type ? Kb : Qb;
    // Q folds softmax scale and log2(e): flash then uses raw exp2.
    const float fscale = type ? 1.0f : 0.125f * 1.44269504f;
    float w0[4];
#pragma unroll
    for (int ni = 0; ni < 4; ++ni) w0[ni] = wnp[ni * 16 + l16];
#pragma unroll
    for (int mi = 0; mi < 4; ++mi) {
#pragma unroll
      for (int r = 0; r < 4; ++r) {
        int s = (tile_m + wm + mi * 16 + quad * 4 + r) & (Ss - 1);
        float ss2 = 0.f;
#pragma unroll
        for (int ni = 0; ni < 4; ++ni) ss2 += acc[mi][ni][r] * acc[mi][ni][r];
        ss2 += __shfl_xor(ss2, 1, 64);
        ss2 += __shfl_xor(ss2, 2, 64);
        ss2 += __shfl_xor(ss2, 4, 64);
        ss2 += __shfl_xor(ss2, 8, 64);
        float rr = rsqrtf(ss2 * (1.0f / 64.0f) + 1e-6f) * fscale;
        float c0 = ct[s * 32 + l16], c1 = ct[s * 32 + 16 + l16];
        float sn0 = st[s * 32 + l16], sn1 = st[s * 32 + 16 + l16];
#pragma unroll
        for (int ni = 0; ni < 4; ++ni) {
          float vn = acc[mi][ni][r] * rr * w0[ni];
          float vp = acc[mi][ni ^ 2][r] * rr * w0[ni ^ 2];
          float cs_ = (ni & 1) ? c1 : c0;
          float sn_ = (ni & 1) ? sn1 : sn0;
          float sg = (ni < 2) ? -1.0f : 1.0f;
          Ob[(bh * Ss + s) * HDd + ni * 16 + l16] = f2bf(vn * cs_ + sg * vp * sn_);
        }
      }
    }
  }
}

// -------- bf16 GEMM 128x64 tile, dbuf K-loop (O-proj: 512 WGs) --------------
__global__ __launch_bounds__(256) void gemm_bt2(
    const unsigned short* __restrict__ A, const unsigned short* __restrict__ Bw,
    float* __restrict__ C, int M, int N, int K) {
  __shared__ __align__(16) unsigned short As[2][128 * 32];  // 8 KB each
  __shared__ __align__(16) unsigned short Bs[2][64 * 32];   // 4 KB each
  const int tid = threadIdx.x;
  const int lane = tid & 63;
  const int quad = lane >> 4;
  const int l16 = lane & 15;
  const int wave = tid >> 6;
  const int wm = (wave >> 1) * 64;
  const int wn = (wave & 1) * 32;
  const int tile_m = blockIdx.y * 128;
  const int tile_n = blockIdx.x * 64;

  const int off0 = tid * 16;
  const int off1 = 4096 + tid * 16;
  const int r0 = tid >> 2, r1 = r0 + 64;
  const int sch = (((tid & 3) ^ ((tid >> 3) & 3)) << 3);
  const int xg = ((quad ^ ((l16 >> 1) & 3)) << 3);

  const unsigned short* Ag0 = A + (size_t)(tile_m + r0) * K + sch;
  const unsigned short* Ag1 = A + (size_t)(tile_m + r1) * K + sch;
  const unsigned short* Bg0 = Bw + (size_t)(tile_n + r0) * K + sch;

  f32x4 zero = {0.f, 0.f, 0.f, 0.f};
  f32x4 acc[4][2];
#pragma unroll
  for (int mi = 0; mi < 4; ++mi)
#pragma unroll
    for (int ni = 0; ni < 2; ++ni) acc[mi][ni] = zero;

  gl_lds16(Ag0, (char*)As[0] + off0);
  gl_lds16(Ag1, (char*)As[0] + off1);
  gl_lds16(Bg0, (char*)Bs[0] + off0);

  const int NIT = 32;  // K/32, K=1024
  for (int it = 0; it < NIT; ++it) {
    __syncthreads();
    if (it + 1 < NIT) {
      const int k1 = (it + 1) * 32, bn = (it + 1) & 1;
      gl_lds16(Ag0 + k1, (char*)As[bn] + off0);
      gl_lds16(Ag1 + k1, (char*)As[bn] + off1);
      gl_lds16(Bg0 + k1, (char*)Bs[bn] + off0);
    }
    const unsigned short* Asb = As[it & 1];
    const unsigned short* Bsb = Bs[it & 1];
    bf16x8 af[4], bfv[2];
#pragma unroll
    for (int mi = 0; mi < 4; ++mi)
      af[mi] = *(const bf16x8*)&Asb[(wm + mi * 16 + l16) * 32 + xg];
#pragma unroll
    for (int ni = 0; ni < 2; ++ni)
      bfv[ni] = *(const bf16x8*)&Bsb[(wn + ni * 16 + l16) * 32 + xg];
#pragma unroll
    for (int mi = 0; mi < 4; ++mi)
#pragma unroll
      for (int ni = 0; ni < 2; ++ni)
        acc[mi][ni] = __builtin_amdgcn_mfma_f32_16x16x32_bf16(
            af[mi], bfv[ni], acc[mi][ni], 0, 0, 0);
  }

#pragma unroll
  for (int mi = 0; mi < 4; ++mi) {
#pragma unroll
    for (int ni = 0; ni < 2; ++ni) {
      int col = tile_n + wn + ni * 16 + l16;
#pragma unroll
      for (int r = 0; r < 4; ++r) {
        int row = tile_m + wm + mi * 16 + quad * 4 + r;
        C[(size_t)row * N + col] = acc[mi][ni][r];
      }
    }
  }
}

// -------- flash attention: S^T form, SW-pipelined K-loop, paired Q-tiles ----
// (byte-identical to R7 — proven replay-stable at <53 us)
__global__ __launch_bounds__(256) void flash(
    const unsigned short* __restrict__ Qb, const unsigned short* __restrict__ Kb,
    const unsigned short* __restrict__ Vt, const float* __restrict__ sink,
    unsigned short* __restrict__ Ob) {
  __shared__ __align__(16) unsigned short Qs[64 * 64];
  __shared__ __align__(16) unsigned short Ks[2][64 * 64];
  __shared__ __align__(16) unsigned short Vs[3][64 * 64];   // V^T tile [d][kv]
  __shared__ __align__(16) unsigned short Ps[4][16 * 72];   // [q][kv], +8 pad

  int tid = threadIdx.x, lane = tid & 63, wave = tid >> 6;
  int quad = lane >> 4, l16 = lane & 15;
  int bx = blockIdx.x;              // 0..15
  int h = blockIdx.y, b = blockIdx.z;

  const unsigned short* Qg = Qb + ((size_t)(b * Hh + h) * Ss) * HDd;
  const unsigned short* Kg = Kb + ((size_t)(b * Hh + h) * Ss) * HDd;
  const unsigned short* Vg = Vt + ((size_t)(b * Hh + h) * HDd) * Ss;

  int off0 = tid * 16, off1 = 4096 + tid * 16;
  int sr0 = tid >> 3, sr1 = sr0 + 32;
  int sch = ((tid & 7) ^ (sr0 & 7)) * 8;   // XOR-swizzled source chunk
  int x0 = ((quad ^ (l16 & 7)) * 8);       // swizzled read offset
  int x1 = x0 ^ 32;

  float sk = sink[h];
  f32x4 zero = {0.f, 0.f, 0.f, 0.f};

  bf16x8 ones;  // all-ones A-frag for l row-sum MFMA
  {
    u16x8 t;
#pragma unroll
    for (int i = 0; i < 8; ++i) t[i] = 0x3F80;  // bf16 1.0
    ones = *(bf16x8*)&t;
  }

#pragma unroll 1
  for (int pass = 0; pass < 2; ++pass) {
    int qt = pass ? bx : 31 - bx;     // long tile first
    int q0 = qt * 64;
    int myq = q0 + wave * 16 + l16;   // this lane's query

    __syncthreads();  // prior pass done with all LDS buffers
    gl_lds16(Qg + (size_t)(q0 + sr0) * 64 + sch, (char*)Qs + off0);
    gl_lds16(Qg + (size_t)(q0 + sr1) * 64 + sch, (char*)Qs + off1);
    gl_lds16(Kg + (size_t)sr0 * 64 + sch, (char*)Ks[0] + off0);
    gl_lds16(Kg + (size_t)sr1 * 64 + sch, (char*)Ks[0] + off1);
    gl_lds16(Vg + (size_t)sr0 * Ss + sch, (char*)Vs[0] + off0);
    gl_lds16(Vg + (size_t)sr1 * Ss + sch, (char*)Vs[0] + off1);

    f32x4 Oacc[4], lacc = zero;
#pragma unroll
    for (int ni = 0; ni < 4; ++ni) Oacc[ni] = zero;

    __syncthreads();  // Q, K0, V0 staged
    bf16x8 aq0 = *(const bf16x8*)&Qs[(wave * 16 + l16) * 64 + x0];
    bf16x8 aq1 = *(const bf16x8*)&Qs[(wave * 16 + l16) * 64 + x1];
    if (qt >= 1) {  // prefetch tile 1
      gl_lds16(Kg + (size_t)(64 + sr0) * 64 + sch, (char*)Ks[1] + off0);
      gl_lds16(Kg + (size_t)(64 + sr1) * 64 + sch, (char*)Ks[1] + off1);
      gl_lds16(Vg + (size_t)sr0 * Ss + 64 + sch, (char*)Vs[1] + off0);
      gl_lds16(Vg + (size_t)sr1 * Ss + 64 + sch, (char*)Vs[1] + off1);
    }

    // QK for kt=0
    f32x4 sc[4];
#pragma unroll
    for (int ni = 0; ni < 4; ++ni) {
      bf16x8 bk0 = *(const bf16x8*)&Ks[0][(ni * 16 + l16) * 64 + x0];
      bf16x8 bk1 = *(const bf16x8*)&Ks[0][(ni * 16 + l16) * 64 + x1];
      sc[ni] = __builtin_amdgcn_mfma_f32_16x16x32_bf16(bk0, aq0, zero, 0, 0, 0);
      sc[ni] = __builtin_amdgcn_mfma_f32_16x16x32_bf16(bk1, aq1, sc[ni], 0, 0, 0);
    }
    if (qt == 0) {
#pragma unroll
      for (int ni = 0; ni < 4; ++ni)
#pragma unroll
        for (int r = 0; r < 4; ++r)
          if (ni * 16 + quad * 4 + r > myq - q0) sc[ni][r] = -1.0e38f;
    }

    for (int kt = 0; kt <= qt; ++kt) {
      bool last = (kt == qt);
      if (!last) __syncthreads();  // K/V[kt+1] staged (drains prefetch)
      if (kt + 2 <= qt) {          // prefetch kt+2 (K dbuf, V tbuf)
        int vb = (kt + 2) % 3, kb = kt & 1;
        gl_lds16(Kg + (size_t)((kt + 2) * 64 + sr0) * 64 + sch, (char*)Ks[kb] + off0);
        gl_lds16(Kg + (size_t)((kt + 2) * 64 + sr1) * 64 + sch, (char*)Ks[kb] + off1);
        gl_lds16(Vg + (size_t)sr0 * Ss + (kt + 2) * 64 + sch, (char*)Vs[vb] + off0);
        gl_lds16(Vg + (size_t)sr1 * Ss + (kt + 2) * 64 + sch, (char*)Vs[vb] + off1);
      }

      // p = exp2(sc[kt]); pack & write P (VALU overlaps next K-frag latency)
#pragma unroll
      for (int ni = 0; ni < 4; ++ni) {
        ushort4 pk;
        pk.x = f2bf_fast(exp2f(sc[ni][0]));
        pk.y = f2bf_fast(exp2f(sc[ni][1]));
        pk.z = f2bf_fast(exp2f(sc[ni][2]));
        pk.w = f2bf_fast(exp2f(sc[ni][3]));
        *(ushort4*)&Ps[wave][l16 * 72 + ni * 16 + quad * 4] = pk;
      }

      // QK for kt+1 (pipelined above PV[kt])
      f32x4 scn[4];
      if (!last) {
        const unsigned short* Kt = Ks[(kt + 1) & 1];
#pragma unroll
        for (int ni = 0; ni < 4; ++ni) {
          bf16x8 bk0 = *(const bf16x8*)&Kt[(ni * 16 + l16) * 64 + x0];
          bf16x8 bk1 = *(const bf16x8*)&Kt[(ni * 16 + l16) * 64 + x1];
          scn[ni] = __builtin_amdgcn_mfma_f32_16x16x32_bf16(bk0, aq0, zero, 0, 0, 0);
          scn[ni] = __builtin_amdgcn_mfma_f32_16x16x32_bf16(bk1, aq1, scn[ni], 0, 0, 0);
        }
        if (kt + 1 == qt) {  // diagonal mask for next tile
#pragma unroll
          for (int ni = 0; ni < 4; ++ni)
#pragma unroll
            for (int r = 0; r < 4; ++r)
              if ((kt + 1) * 64 + ni * 16 + quad * 4 + r > myq) scn[ni][r] = -1.0e38f;
        }
      }

      asm volatile("s_waitcnt lgkmcnt(0)" ::: "memory");  // P visible in-wave
      bf16x8 ap0 = *(const bf16x8*)&Ps[wave][l16 * 72 + quad * 8];
      bf16x8 ap1 = *(const bf16x8*)&Ps[wave][l16 * 72 + 32 + quad * 8];

      // O^T[d][q] += V^T·P^T ; l row-sum via ones-frag MFMA
      const unsigned short* Vtile = Vs[kt % 3];
#pragma unroll
      for (int ni = 0; ni < 4; ++ni) {
        bf16x8 bv0 = *(const bf16x8*)&Vtile[(ni * 16 + l16) * 64 + x0];
        bf16x8 bv1 = *(const bf16x8*)&Vtile[(ni * 16 + l16) * 64 + x1];
        Oacc[ni] = __builtin_amdgcn_mfma_f32_16x16x32_bf16(bv0, ap0, Oacc[ni], 0, 0, 0);
        Oacc[ni] = __builtin_amdgcn_mfma_f32_16x16x32_bf16(bv1, ap1, Oacc[ni], 0, 0, 0);
      }
      lacc = __builtin_amdgcn_mfma_f32_16x16x32_bf16(ones, ap0, lacc, 0, 0, 0);
      lacc = __builtin_amdgcn_mfma_f32_16x16x32_bf16(ones, ap1, lacc, 0, 0, 0);

      if (!last) {
#pragma unroll
        for (int ni = 0; ni < 4; ++ni) sc[ni] = scn[ni];
      }
    }

    // epilogue: every lane already holds l(q=myq) in lacc[0]
    float inv = 1.0f / (lacc[0] + exp2f(sk * 1.44269504f));
#pragma unroll
    for (int ni = 0; ni < 4; ++ni) {
      ushort4 ov;
      ov.x = f2bf(Oacc[ni][0] * inv);
      ov.y = f2bf(Oacc[ni][1] * inv);
      ov.z = f2bf(Oacc[ni][2] * inv);
      ov.w = f2bf(Oacc[ni][3] * inv);
      *(ushort4*)&Ob[((size_t)b * Ss + myq) * Dd + h * 64 + ni * 16 + quad * 4] = ov;
    }
  }
}

extern "C" void kernel_launch(void* const* d_in, const int* in_sizes, int n_in,
                              void* d_out, int out_size, void* d_ws, size_t ws_size,
                              hipStream_t stream) {
  const float* x  = (const float*)d_in[0];
  const float* wq = (const float*)d_in[1];
  const float* wk = (const float*)d_in[2];
  const float* wv = (const float*)d_in[3];
  const float* wo = (const float*)d_in[4];
  const float* qw = (const float*)d_in[5];
  const float* kw = (const float*)d_in[6];
  const float* sk = (const float*)d_in[7];

  char* ws = (char*)d_ws;
  const size_t MB = 1ull << 20;
  unsigned short* xb    = (unsigned short*)(ws + 0);       // 8 MB (dead after gemm_qkv)
  unsigned short* attnb = (unsigned short*)(ws + 0);       // 8 MB (after flash)
  unsigned short* wqkvb = (unsigned short*)(ws + 8 * MB);  // 6 MB
  unsigned short* wob   = (unsigned short*)(ws + 14 * MB); // 2 MB
  float*          ct    = (float*)(ws + 16 * MB);          // 256 KB
  float*          st    = (float*)(ws + 17 * MB);          // 256 KB
  unsigned short* Qb    = (unsigned short*)(ws + 40 * MB); // 8 MB
  unsigned short* Kb    = (unsigned short*)(ws + 48 * MB); // 8 MB
  unsigned short* Vt    = (unsigned short*)(ws + 56 * MB); // 8 MB

  cast_all<<<8448, 256, 0, stream>>>(
      (const float4*)x, (const float4*)wq, (const float4*)wk, (const float4*)wv,
      (const float4*)wo, (ushort4*)xb, (ushort4*)wqkvb, (ushort4*)wob, ct, st);
  gemm_qkv<<<dim3(24, 32), 256, 0, stream>>>(xb, wqkvb, qw, kw, ct, st, Qb, Kb, Vt);
  flash<<<dim3(16, Hh, Bb), 256, 0, stream>>>(Qb, Kb, Vt, sk, attnb);
  gemm_bt2<<<dim3(16, 32), 256, 0, stream>>>(attnb, wob, (float*)d_out, BS, Dd, Dd);
}

// Round 10
// 202.766 us; speedup vs baseline: 1.0288x; 1.0288x over previous
//
#include <hip/hip_runtime.h>

#define Bb 2
#define Ss 2048
#define Dd 1024
#define Hh 16
#define HDd 64
#define BS (Bb * Ss)

typedef __attribute__((ext_vector_type(8))) __bf16 bf16x8;
typedef __attribute__((ext_vector_type(8))) unsigned short u16x8;
typedef __attribute__((ext_vector_type(4))) float f32x4;

__device__ __forceinline__ unsigned short f2bf(float f) {
  union { float f; unsigned u; } v; v.f = f;
  unsigned r = v.u + 0x7fffu + ((v.u >> 16) & 1u);
  return (unsigned short)(r >> 16);
}
__device__ __forceinline__ unsigned short f2bf_fast(float f) {  // RN, no tie fix
  union { float f; unsigned u; } v; v.f = f;
  return (unsigned short)((v.u + 0x8000u) >> 16);
}

// async global->LDS, 16B per lane; LDS dest = wave-uniform base + lane*16.
// R8 lesson: keep <=4 in flight per thread (8 outstanding raced on replay).
__device__ __forceinline__ void gl_lds16(const void* g, void* l) {
  __builtin_amdgcn_global_load_lds(
      (const __attribute__((address_space(1))) void*)g,
      (__attribute__((address_space(3))) void*)l, 16, 0, 0);
}

// -------- cast fp32 -> bf16 (x, wq|wk|wv stacked, wo) + RoPE cos/sin table --
__global__ __launch_bounds__(256) void cast_all(
    const float4* __restrict__ x, const float4* __restrict__ wq,
    const float4* __restrict__ wk, const float4* __restrict__ wv,
    const float4* __restrict__ wo, ushort4* __restrict__ xb,
    ushort4* __restrict__ wqkvb, ushort4* __restrict__ wob,
    float* __restrict__ ct, float* __restrict__ st) {
  int i = blockIdx.x * 256 + threadIdx.x;
  const int NX4 = BS * Dd / 4;   // 1M
  const int NW4 = Dd * Dd / 4;   // 256K
  const float4* src;
  ushort4* dst;
  int idx;
  if (i < NX4) { src = x; dst = xb; idx = i; }
  else if ((i -= NX4) < NW4) { src = wq; dst = wqkvb; idx = i; }
  else if ((i -= NW4) < NW4) { src = wk; dst = wqkvb + NW4; idx = i; }
  else if ((i -= NW4) < NW4) { src = wv; dst = wqkvb + 2 * NW4; idx = i; }
  else if ((i -= NW4) < NW4) { src = wo; dst = wob; idx = i; }
  else if ((i -= NW4) < Ss * 32) {  // RoPE table: i = s*32 + j
    int s = i >> 5, jj = i & 31;
    float freq = __powf(10000.0f, -(float)jj * (1.0f / 32.0f));
    float cs, sn;
    sincosf((float)s * freq, &sn, &cs);
    ct[i] = cs; st[i] = sn;
    return;
  } else return;
  float4 v = src[idx];
  ushort4 o;
  o.x = f2bf(v.x); o.y = f2bf(v.y); o.z = f2bf(v.z); o.w = f2bf(v.w);
  dst[idx] = o;
}

// -------- fused QKV GEMM + QK-RMSNorm + RoPE + layout (R7 verbatim) ---------
// BK=32 single-buffer: BK=64 (R8) raced, LDS dbuf (R9) regressed (compiler
// drains vmcnt before ds_reads it can't prove non-aliased with DMA).
__global__ __launch_bounds__(256) void gemm_qkv(
    const unsigned short* __restrict__ A, const unsigned short* __restrict__ Bw,
    const float* __restrict__ qw, const float* __restrict__ kw,
    const float* __restrict__ ct, const float* __restrict__ st,
    unsigned short* __restrict__ Qb, unsigned short* __restrict__ Kb,
    unsigned short* __restrict__ Vt) {
  __shared__ __align__(16) unsigned short As[128 * 32];
  __shared__ __align__(16) unsigned short Bs[128 * 32];
  const int K = Dd, tid = threadIdx.x;
  const int lane = tid & 63;
  const int quad = lane >> 4;
  const int l16 = lane & 15;
  const int wave = tid >> 6;
  const int wm = (wave >> 1) * 64;
  const int wn = (wave & 1) * 64;
  const int tile_m = blockIdx.y * 128;
  const int tile_n = blockIdx.x * 128;

  const int off0 = tid * 16;
  const int off1 = 4096 + tid * 16;
  const int r0 = tid >> 2, r1 = r0 + 64;
  const int sch = (((tid & 3) ^ ((tid >> 3) & 3)) << 3);  // swizzled src elem
  const int xg = ((quad ^ ((l16 >> 1) & 3)) << 3);        // swizzled read elem

  const unsigned short* Ag0 = A + (size_t)(tile_m + r0) * K + sch;
  const unsigned short* Ag1 = A + (size_t)(tile_m + r1) * K + sch;
  const unsigned short* Bg0 = Bw + (size_t)(tile_n + r0) * K + sch;
  const unsigned short* Bg1 = Bw + (size_t)(tile_n + r1) * K + sch;

  f32x4 zero = {0.f, 0.f, 0.f, 0.f};
  f32x4 acc[4][4];
#pragma unroll
  for (int mi = 0; mi < 4; ++mi)
#pragma unroll
    for (int ni = 0; ni < 4; ++ni) acc[mi][ni] = zero;

  for (int k0 = 0; k0 < K; k0 += 32) {
    gl_lds16(Ag0 + k0, (char*)As + off0);
    gl_lds16(Ag1 + k0, (char*)As + off1);
    gl_lds16(Bg0 + k0, (char*)Bs + off0);
    gl_lds16(Bg1 + k0, (char*)Bs + off1);
    __syncthreads();
    bf16x8 af[4], bfv[4];
#pragma unroll
    for (int mi = 0; mi < 4; ++mi)
      af[mi] = *(const bf16x8*)&As[(wm + mi * 16 + l16) * 32 + xg];
#pragma unroll
    for (int ni = 0; ni < 4; ++ni)
      bfv[ni] = *(const bf16x8*)&Bs[(wn + ni * 16 + l16) * 32 + xg];
#pragma unroll
    for (int mi = 0; mi < 4; ++mi)
#pragma unroll
      for (int ni = 0; ni < 4; ++ni)
        acc[mi][ni] = __builtin_amdgcn_mfma_f32_16x16x32_bf16(
            af[mi], bfv[ni], acc[mi][ni], 0, 0, 0);
    __syncthreads();
  }

  // ---- fused epilogue. C-layout: row = wm+mi*16+quad*4+r, col = wn+ni*16+l16
  const int type = blockIdx.x >> 3;                    // 0=Q,1=K,2=V
  const int h = (((blockIdx.x & 7) << 7) + wn) >> 6;   // head index
  const int bb = tile_m >> 11;
  const size_t bh = (size_t)bb * Hh + h;

  if (type == 2) {  // V: transpose store Vt[bh][d][s], pack 4 tokens
#pragma unroll
    for (int mi = 0; mi < 4; ++mi) {
      int s0 = (tile_m + wm + mi * 16 + quad * 4) & (Ss - 1);
#pragma unroll
      for (int ni = 0; ni < 4; ++ni) {
        int d = ni * 16 + l16;
        ushort4 pv;
        pv.x = f2bf(acc[mi][ni][0]);
        pv.y = f2bf(acc[mi][ni][1]);
        pv.z = f2bf(acc[mi][ni][2]);
        pv.w = f2bf(acc[mi][ni][3]);
        *(ushort4*)&Vt[(bh * HDd + d) * Ss + s0] = pv;
      }
    }
  } else {
    const float* wnp = type ? kw : qw;
    unsigned short* Ob = type ? Kb : Qb;
    // Q folds softmax scale and log2(e): flash then uses raw exp2.
    const float fscale = type ? 1.0f : 0.125f * 1.44269504f;
    float w0[4];
#pragma unroll
    for (int ni = 0; ni < 4; ++ni) w0[ni] = wnp[ni * 16 + l16];
#pragma unroll
    for (int mi = 0; mi < 4; ++mi) {
#pragma unroll
      for (int r = 0; r < 4; ++r) {
        int s = (tile_m + wm + mi * 16 + quad * 4 + r) & (Ss - 1);
        float ss2 = 0.f;
#pragma unroll
        for (int ni = 0; ni < 4; ++ni) ss2 += acc[mi][ni][r] * acc[mi][ni][r];
        ss2 += __shfl_xor(ss2, 1, 64);
        ss2 += __shfl_xor(ss2, 2, 64);
        ss2 += __shfl_xor(ss2, 4, 64);
        ss2 += __shfl_xor(ss2, 8, 64);
        float rr = rsqrtf(ss2 * (1.0f / 64.0f) + 1e-6f) * fscale;
        float c0 = ct[s * 32 + l16], c1 = ct[s * 32 + 16 + l16];
        float sn0 = st[s * 32 + l16], sn1 = st[s * 32 + 16 + l16];
#pragma unroll
        for (int ni = 0; ni < 4; ++ni) {
          float vn = acc[mi][ni][r] * rr * w0[ni];
          float vp = acc[mi][ni ^ 2][r] * rr * w0[ni ^ 2];
          float cs_ = (ni & 1) ? c1 : c0;
          float sn_ = (ni & 1) ? sn1 : sn0;
          float sg = (ni < 2) ? -1.0f : 1.0f;
          Ob[(bh * Ss + s) * HDd + ni * 16 + l16] = f2bf(vn * cs_ + sg * vp * sn_);
        }
      }
    }
  }
}

// -------- bf16 GEMM 128x64 tile (R7 verbatim; O-proj: 512 WGs) --------------
__global__ __launch_bounds__(256) void gemm_bt2(
    const unsigned short* __restrict__ A, const unsigned short* __restrict__ Bw,
    float* __restrict__ C, int M, int N, int K) {
  __shared__ __align__(16) unsigned short As[128 * 32];
  __shared__ __align__(16) unsigned short Bs[64 * 32];
  const int tid = threadIdx.x;
  const int lane = tid & 63;
  const int quad = lane >> 4;
  const int l16 = lane & 15;
  const int wave = tid >> 6;
  const int wm = (wave >> 1) * 64;
  const int wn = (wave & 1) * 32;
  const int tile_m = blockIdx.y * 128;
  const int tile_n = blockIdx.x * 64;

  const int off0 = tid * 16;
  const int off1 = 4096 + tid * 16;
  const int r0 = tid >> 2, r1 = r0 + 64;
  const int sch = (((tid & 3) ^ ((tid >> 3) & 3)) << 3);
  const int xg = ((quad ^ ((l16 >> 1) & 3)) << 3);

  const unsigned short* Ag0 = A + (size_t)(tile_m + r0) * K + sch;
  const unsigned short* Ag1 = A + (size_t)(tile_m + r1) * K + sch;
  const unsigned short* Bg0 = Bw + (size_t)(tile_n + r0) * K + sch;

  f32x4 zero = {0.f, 0.f, 0.f, 0.f};
  f32x4 acc[4][2];
#pragma unroll
  for (int mi = 0; mi < 4; ++mi)
#pragma unroll
    for (int ni = 0; ni < 2; ++ni) acc[mi][ni] = zero;

  for (int k0 = 0; k0 < K; k0 += 32) {
    gl_lds16(Ag0 + k0, (char*)As + off0);
    gl_lds16(Ag1 + k0, (char*)As + off1);
    gl_lds16(Bg0 + k0, (char*)Bs + off0);
    __syncthreads();
    bf16x8 af[4], bfv[2];
#pragma unroll
    for (int mi = 0; mi < 4; ++mi)
      af[mi] = *(const bf16x8*)&As[(wm + mi * 16 + l16) * 32 + xg];
#pragma unroll
    for (int ni = 0; ni < 2; ++ni)
      bfv[ni] = *(const bf16x8*)&Bs[(wn + ni * 16 + l16) * 32 + xg];
#pragma unroll
    for (int mi = 0; mi < 4; ++mi)
#pragma unroll
      for (int ni = 0; ni < 2; ++ni)
        acc[mi][ni] = __builtin_amdgcn_mfma_f32_16x16x32_bf16(
            af[mi], bfv[ni], acc[mi][ni], 0, 0, 0);
    __syncthreads();
  }

#pragma unroll
  for (int mi = 0; mi < 4; ++mi) {
#pragma unroll
    for (int ni = 0; ni < 2; ++ni) {
      int col = tile_n + wn + ni * 16 + l16;
#pragma unroll
      for (int r = 0; r < 4; ++r) {
        int row = tile_m + wm + mi * 16 + quad * 4 + r;
        C[(size_t)row * N + col] = acc[mi][ni][r];
      }
    }
  }
}

// -------- flash attention: 512-thread WG, two 4-wave halves share K/V -------
// Halves process Q-tiles (qtBig, qtBig-1) off the SAME K/V LDS tiles: staging
// bytes and barrier count per unit compute halve vs R7. 2-pass pairing keeps
// every WG at exactly 34 kv-iterations (pass0: qtBig=31-2bx, pass1: 2bx+1).
// R7's SW pipeline retained (QK[kt+1] above PV[kt], K dbuf, V tbuf).
// P overlays the dead Q tile (Q is in regs after kt=0's barrier) in the
// R4-validated XOR-swizzled stride-64 layout -> LDS 56 KB. l via ones-MFMA.
__global__ __launch_bounds__(512) void flash(
    const unsigned short* __restrict__ Qb, const unsigned short* __restrict__ Kb,
    const unsigned short* __restrict__ Vt, const float* __restrict__ sink,
    unsigned short* __restrict__ Ob) {
  __shared__ __align__(16) unsigned short QP[8192];         // 2 Q tiles / 8 P regions
  __shared__ __align__(16) unsigned short Ks[2][64 * 64];
  __shared__ __align__(16) unsigned short Vs[3][64 * 64];   // V^T tile [d][kv]

  int tid = threadIdx.x, lane = tid & 63, wave = tid >> 6;  // wave 0..7
  int half = wave >> 2, wl = wave & 3;
  int quad = lane >> 4, l16 = lane & 15;
  int bx = blockIdx.x;              // 0..7
  int h = blockIdx.y, b = blockIdx.z;

  const unsigned short* Qg = Qb + ((size_t)(b * Hh + h) * Ss) * HDd;
  const unsigned short* Kg = Kb + ((size_t)(b * Hh + h) * Ss) * HDd;
  const unsigned short* Vg = Vt + ((size_t)(b * Hh + h) * HDd) * Ss;

  int off = tid * 16;
  int sr = tid >> 3;                       // 0..63: one 8KB tile per round
  int sch = ((tid & 7) ^ (sr & 7)) * 8;    // XOR-swizzled source chunk
  int x0 = ((quad ^ (l16 & 7)) * 8);       // swizzled read offset
  int x1 = x0 ^ 32;

  unsigned short* Pw = QP + wave * 1024;   // this wave's 16x64 P region
  float sk = sink[h];
  f32x4 zero = {0.f, 0.f, 0.f, 0.f};

  bf16x8 ones;  // all-ones A-frag for l row-sum MFMA
  {
    u16x8 t;
#pragma unroll
    for (int i = 0; i < 8; ++i) t[i] = 0x3F80;  // bf16 1.0
    ones = *(bf16x8*)&t;
  }

#pragma unroll 1
  for (int pass = 0; pass < 2; ++pass) {
    int qtBig = pass ? (2 * bx + 1) : (31 - 2 * bx);
    int qth = qtBig - half;           // half0: qtBig, half1: qtBig-1
    int myq = qth * 64 + wl * 16 + l16;

    __syncthreads();  // prior pass done with all LDS buffers
    gl_lds16(Qg + (size_t)(qtBig * 64 + sr) * 64 + sch, (char*)QP + off);
    gl_lds16(Qg + (size_t)((qtBig - 1) * 64 + sr) * 64 + sch, (char*)QP + 8192 + off);
    gl_lds16(Kg + (size_t)sr * 64 + sch, (char*)Ks[0] + off);
    gl_lds16(Vg + (size_t)sr * Ss + sch, (char*)Vs[0] + off);

    f32x4 Oacc[4], lacc = zero;
#pragma unroll
    for (int ni = 0; ni < 4; ++ni) Oacc[ni] = zero;

    __syncthreads();  // Q(both), K0, V0 staged
    bf16x8 aq0 = *(const bf16x8*)&QP[(half * 64 + wl * 16 + l16) * 64 + x0];
    bf16x8 aq1 = *(const bf16x8*)&QP[(half * 64 + wl * 16 + l16) * 64 + x1];
    // prefetch tile 1 (qtBig >= 1 always)
    gl_lds16(Kg + (size_t)(64 + sr) * 64 + sch, (char*)Ks[1] + off);
    gl_lds16(Vg + (size_t)sr * Ss + 64 + sch, (char*)Vs[1] + off);

    // QK for kt=0 (kt=0 <= qth for both halves)
    f32x4 sc[4];
#pragma unroll
    for (int ni = 0; ni < 4; ++ni) {
      bf16x8 bk0 = *(const bf16x8*)&Ks[0][(ni * 16 + l16) * 64 + x0];
      bf16x8 bk1 = *(const bf16x8*)&Ks[0][(ni * 16 + l16) * 64 + x1];
      sc[ni] = __builtin_amdgcn_mfma_f32_16x16x32_bf16(bk0, aq0, zero, 0, 0, 0);
      sc[ni] = __builtin_amdgcn_mfma_f32_16x16x32_bf16(bk1, aq1, sc[ni], 0, 0, 0);
    }
    if (qth == 0) {  // diagonal at kt=0 (only pass1 bx=0 half1)
#pragma unroll
      for (int ni = 0; ni < 4; ++ni)
#pragma unroll
        for (int r = 0; r < 4; ++r)
          if (ni * 16 + quad * 4 + r > myq) sc[ni][r] = -1.0e38f;
    }

    for (int kt = 0; kt <= qtBig; ++kt) {
      bool lastBig = (kt == qtBig);
      bool active = (kt <= qth);      // wave-uniform
      bool pipeN = (kt + 1 <= qth);
      if (!lastBig) __syncthreads();  // K/V[kt+1] staged; P region writable
      if (kt + 2 <= qtBig) {          // prefetch kt+2 (K dbuf, V tbuf)
        gl_lds16(Kg + (size_t)((kt + 2) * 64 + sr) * 64 + sch, (char*)Ks[kt & 1] + off);
        gl_lds16(Vg + (size_t)sr * Ss + (kt + 2) * 64 + sch, (char*)Vs[(kt + 2) % 3] + off);
      }

      // p = exp2(sc[kt]) -> P (swizzled stride-64: chunk c at c^(l16&7))
      if (active) {
#pragma unroll
        for (int ni = 0; ni < 4; ++ni) {
          ushort4 pk;
          pk.x = f2bf_fast(exp2f(sc[ni][0]));
          pk.y = f2bf_fast(exp2f(sc[ni][1]));
          pk.z = f2bf_fast(exp2f(sc[ni][2]));
          pk.w = f2bf_fast(exp2f(sc[ni][3]));
          int slot = ((ni * 2 + (quad >> 1)) ^ (l16 & 7)) * 8 + (quad & 1) * 4;
          *(ushort4*)&Pw[l16 * 64 + slot] = pk;
        }
      }

      // QK for kt+1 (pipelined above PV[kt])
      f32x4 scn[4];
      if (pipeN) {
        const unsigned short* Kt = Ks[(kt + 1) & 1];
#pragma unroll
        for (int ni = 0; ni < 4; ++ni) {
          bf16x8 bk0 = *(const bf16x8*)&Kt[(ni * 16 + l16) * 64 + x0];
          bf16x8 bk1 = *(const bf16x8*)&Kt[(ni * 16 + l16) * 64 + x1];
          scn[ni] = __builtin_amdgcn_mfma_f32_16x16x32_bf16(bk0, aq0, zero, 0, 0, 0);
          scn[ni] = __builtin_amdgcn_mfma_f32_16x16x32_bf16(bk1, aq1, scn[ni], 0, 0, 0);
        }
        if (kt + 1 == qth) {  // diagonal mask for next tile
#pragma unroll
          for (int ni = 0; ni < 4; ++ni)
#pragma unroll
            for (int r = 0; r < 4; ++r)
              if ((kt + 1) * 64 + ni * 16 + quad * 4 + r > myq) scn[ni][r] = -1.0e38f;
        }
      }

      if (active) {
        asm volatile("s_waitcnt lgkmcnt(0)" ::: "memory");  // P visible in-wave
        bf16x8 ap0 = *(const bf16x8*)&Pw[l16 * 64 + x0];
        bf16x8 ap1 = *(const bf16x8*)&Pw[l16 * 64 + x1];

        // O^T[d][q] += V^T·P^T ; l row-sum via ones-frag MFMA
        const unsigned short* Vtile = Vs[kt % 3];
#pragma unroll
        for (int ni = 0; ni < 4; ++ni) {
          bf16x8 bv0 = *(const bf16x8*)&Vtile[(ni * 16 + l16) * 64 + x0];
          bf16x8 bv1 = *(const bf16x8*)&Vtile[(ni * 16 + l16) * 64 + x1];
          Oacc[ni] = __builtin_amdgcn_mfma_f32_16x16x32_bf16(bv0, ap0, Oacc[ni], 0, 0, 0);
          Oacc[ni] = __builtin_amdgcn_mfma_f32_16x16x32_bf16(bv1, ap1, Oacc[ni], 0, 0, 0);
        }
        lacc = __builtin_amdgcn_mfma_f32_16x16x32_bf16(ones, ap0, lacc, 0, 0, 0);
        lacc = __builtin_amdgcn_mfma_f32_16x16x32_bf16(ones, ap1, lacc, 0, 0, 0);
      }

      if (pipeN) {
#pragma unroll
        for (int ni = 0; ni < 4; ++ni) sc[ni] = scn[ni];
      }
    }

    // epilogue: every lane holds l(q=myq) in lacc[0]
    float inv = 1.0f / (lacc[0] + exp2f(sk * 1.44269504f));
#pragma unroll
    for (int ni = 0; ni < 4; ++ni) {
      ushort4 ov;
      ov.x = f2bf(Oacc[ni][0] * inv);
      ov.y = f2bf(Oacc[ni][1] * inv);
      ov.z = f2bf(Oacc[ni][2] * inv);
      ov.w = f2bf(Oacc[ni][3] * inv);
      *(ushort4*)&Ob[((size_t)b * Ss + myq) * Dd + h * 64 + ni * 16 + quad * 4] = ov;
    }
  }
}

extern "C" void kernel_launch(void* const* d_in, const int* in_sizes, int n_in,
                              void* d_out, int out_size, void* d_ws, size_t ws_size,
                              hipStream_t stream) {
  const float* x  = (const float*)d_in[0];
  const float* wq = (const float*)d_in[1];
  const float* wk = (const float*)d_in[2];
  const float* wv = (const float*)d_in[3];
  const float* wo = (const float*)d_in[4];
  const float* qw = (const float*)d_in[5];
  const float* kw = (const float*)d_in[6];
  const float* sk = (const float*)d_in[7];

  char* ws = (char*)d_ws;
  const size_t MB = 1ull << 20;
  unsigned short* xb    = (unsigned short*)(ws + 0);       // 8 MB (dead after gemm_qkv)
  unsigned short* attnb = (unsigned short*)(ws + 0);       // 8 MB (after flash)
  unsigned short* wqkvb = (unsigned short*)(ws + 8 * MB);  // 6 MB
  unsigned short* wob   = (unsigned short*)(ws + 14 * MB); // 2 MB
  float*          ct    = (float*)(ws + 16 * MB);          // 256 KB
  float*          st    = (float*)(ws + 17 * MB);          // 256 KB
  unsigned short* Qb    = (unsigned short*)(ws + 40 * MB); // 8 MB
  unsigned short* Kb    = (unsigned short*)(ws + 48 * MB); // 8 MB
  unsigned short* Vt    = (unsigned short*)(ws + 56 * MB); // 8 MB

  cast_all<<<8448, 256, 0, stream>>>(
      (const float4*)x, (const float4*)wq, (const float4*)wk, (const float4*)wv,
      (const float4*)wo, (ushort4*)xb, (ushort4*)wqkvb, (ushort4*)wob, ct, st);
  gemm_qkv<<<dim3(24, 32), 256, 0, stream>>>(xb, wqkvb, qw, kw, ct, st, Qb, Kb, Vt);
  flash<<<dim3(8, Hh, Bb), 512, 0, stream>>>(Qb, Kb, Vt, sk, attnb);
  gemm_bt2<<<dim3(16, 32), 256, 0, stream>>>(attnb, wob, (float*)d_out, BS, Dd, Dd);
}

// Round 11
// 186.873 us; speedup vs baseline: 1.1163x; 1.0850x over previous
//
#include <hip/hip_runtime.h>

#define Bb 2
#define Ss 2048
#define Dd 1024
#define Hh 16
#define HDd 64
#define BS (Bb * Ss)

typedef __attribute__((ext_vector_type(8))) __bf16 bf16x8;
typedef __attribute__((ext_vector_type(8))) unsigned short u16x8;
typedef __attribute__((ext_vector_type(4))) float f32x4;

__device__ __forceinline__ unsigned short f2bf(float f) {
  union { float f; unsigned u; } v; v.f = f;
  unsigned r = v.u + 0x7fffu + ((v.u >> 16) & 1u);
  return (unsigned short)(r >> 16);
}
__device__ __forceinline__ unsigned short f2bf_fast(float f) {  // RN, no tie fix
  union { float f; unsigned u; } v; v.f = f;
  return (unsigned short)((v.u + 0x8000u) >> 16);
}

// async global->LDS, 16B per lane; LDS dest = wave-uniform base + lane*16.
// R8 lesson: keep <=4 in flight per thread (8 outstanding raced on replay).
__device__ __forceinline__ void gl_lds16(const void* g, void* l) {
  __builtin_amdgcn_global_load_lds(
      (const __attribute__((address_space(1))) void*)g,
      (__attribute__((address_space(3))) void*)l, 16, 0, 0);
}

// -------- cast fp32 -> bf16 (x, wq|wk|wv stacked, wo) + RoPE cos/sin table --
__global__ __launch_bounds__(256) void cast_all(
    const float4* __restrict__ x, const float4* __restrict__ wq,
    const float4* __restrict__ wk, const float4* __restrict__ wv,
    const float4* __restrict__ wo, ushort4* __restrict__ xb,
    ushort4* __restrict__ wqkvb, ushort4* __restrict__ wob,
    float* __restrict__ ct, float* __restrict__ st) {
  int i = blockIdx.x * 256 + threadIdx.x;
  const int NX4 = BS * Dd / 4;   // 1M
  const int NW4 = Dd * Dd / 4;   // 256K
  const float4* src;
  ushort4* dst;
  int idx;
  if (i < NX4) { src = x; dst = xb; idx = i; }
  else if ((i -= NX4) < NW4) { src = wq; dst = wqkvb; idx = i; }
  else if ((i -= NW4) < NW4) { src = wk; dst = wqkvb + NW4; idx = i; }
  else if ((i -= NW4) < NW4) { src = wv; dst = wqkvb + 2 * NW4; idx = i; }
  else if ((i -= NW4) < NW4) { src = wo; dst = wob; idx = i; }
  else if ((i -= NW4) < Ss * 32) {  // RoPE table: i = s*32 + j
    int s = i >> 5, jj = i & 31;
    float freq = __powf(10000.0f, -(float)jj * (1.0f / 32.0f));
    float cs, sn;
    sincosf((float)s * freq, &sn, &cs);
    ct[i] = cs; st[i] = sn;
    return;
  } else return;
  float4 v = src[idx];
  ushort4 o;
  o.x = f2bf(v.x); o.y = f2bf(v.y); o.z = f2bf(v.z); o.w = f2bf(v.w);
  dst[idx] = o;
}

// -------- fused QKV GEMM + QK-RMSNorm + RoPE + layout -----------------------
// R11: __launch_bounds__(256, 3) — with 64 acc-AGPRs (unified file), the old
// VGPR_Count=116 put total regs ~180 -> 2 waves/SIMD -> 2 WGs/CU and a 1.5-
// round makespan for the 768-WG grid. Capping at 3 waves/SIMD (<=~170 total)
// gives 3 WGs/CU = one clean dispatch round + 50% more TLP to hide drains.
// BK=32 single-buffer (BK=64 raced R8; LDS dbuf regressed R9).
__global__ __launch_bounds__(256, 3) void gemm_qkv(
    const unsigned short* __restrict__ A, const unsigned short* __restrict__ Bw,
    const float* __restrict__ qw, const float* __restrict__ kw,
    const float* __restrict__ ct, const float* __restrict__ st,
    unsigned short* __restrict__ Qb, unsigned short* __restrict__ Kb,
    unsigned short* __restrict__ Vt) {
  __shared__ __align__(16) unsigned short As[128 * 32];
  __shared__ __align__(16) unsigned short Bs[128 * 32];
  const int K = Dd, tid = threadIdx.x;
  const int lane = tid & 63;
  const int quad = lane >> 4;
  const int l16 = lane & 15;
  const int wave = tid >> 6;
  const int wm = (wave >> 1) * 64;
  const int wn = (wave & 1) * 64;
  const int tile_m = blockIdx.y * 128;
  const int tile_n = blockIdx.x * 128;

  const int off0 = tid * 16;
  const int off1 = 4096 + tid * 16;
  const int r0 = tid >> 2, r1 = r0 + 64;
  const int sch = (((tid & 3) ^ ((tid >> 3) & 3)) << 3);  // swizzled src elem
  const int xg = ((quad ^ ((l16 >> 1) & 3)) << 3);        // swizzled read elem

  const unsigned short* Ag0 = A + (size_t)(tile_m + r0) * K + sch;
  const unsigned short* Ag1 = A + (size_t)(tile_m + r1) * K + sch;
  const unsigned short* Bg0 = Bw + (size_t)(tile_n + r0) * K + sch;
  const unsigned short* Bg1 = Bw + (size_t)(tile_n + r1) * K + sch;

  f32x4 zero = {0.f, 0.f, 0.f, 0.f};
  f32x4 acc[4][4];
#pragma unroll
  for (int mi = 0; mi < 4; ++mi)
#pragma unroll
    for (int ni = 0; ni < 4; ++ni) acc[mi][ni] = zero;

  for (int k0 = 0; k0 < K; k0 += 32) {
    gl_lds16(Ag0 + k0, (char*)As + off0);
    gl_lds16(Ag1 + k0, (char*)As + off1);
    gl_lds16(Bg0 + k0, (char*)Bs + off0);
    gl_lds16(Bg1 + k0, (char*)Bs + off1);
    __syncthreads();
    bf16x8 af[4], bfv[4];
#pragma unroll
    for (int mi = 0; mi < 4; ++mi)
      af[mi] = *(const bf16x8*)&As[(wm + mi * 16 + l16) * 32 + xg];
#pragma unroll
    for (int ni = 0; ni < 4; ++ni)
      bfv[ni] = *(const bf16x8*)&Bs[(wn + ni * 16 + l16) * 32 + xg];
#pragma unroll
    for (int mi = 0; mi < 4; ++mi)
#pragma unroll
      for (int ni = 0; ni < 4; ++ni)
        acc[mi][ni] = __builtin_amdgcn_mfma_f32_16x16x32_bf16(
            af[mi], bfv[ni], acc[mi][ni], 0, 0, 0);
    __syncthreads();
  }

  // ---- fused epilogue. C-layout: row = wm+mi*16+quad*4+r, col = wn+ni*16+l16
  const int type = blockIdx.x >> 3;                    // 0=Q,1=K,2=V
  const int h = (((blockIdx.x & 7) << 7) + wn) >> 6;   // head index
  const int bb = tile_m >> 11;
  const size_t bh = (size_t)bb * Hh + h;

  if (type == 2) {  // V: transpose store Vt[bh][d][s], pack 4 tokens
#pragma unroll
    for (int mi = 0; mi < 4; ++mi) {
      int s0 = (tile_m + wm + mi * 16 + quad * 4) & (Ss - 1);
#pragma unroll
      for (int ni = 0; ni < 4; ++ni) {
        int d = ni * 16 + l16;
        ushort4 pv;
        pv.x = f2bf(acc[mi][ni][0]);
        pv.y = f2bf(acc[mi][ni][1]);
        pv.z = f2bf(acc[mi][ni][2]);
        pv.w = f2bf(acc[mi][ni][3]);
        *(ushort4*)&Vt[(bh * HDd + d) * Ss + s0] = pv;
      }
    }
  } else {
    const float* wnp = type ? kw : qw;
    unsigned short* Ob = type ? Kb : Qb;
    // Q folds softmax scale and log2(e): flash then uses raw exp2.
    const float fscale = type ? 1.0f : 0.125f * 1.44269504f;
    float w0[4];
#pragma unroll
    for (int ni = 0; ni < 4; ++ni) w0[ni] = wnp[ni * 16 + l16];
#pragma unroll
    for (int mi = 0; mi < 4; ++mi) {
#pragma unroll
      for (int r = 0; r < 4; ++r) {
        int s = (tile_m + wm + mi * 16 + quad * 4 + r) & (Ss - 1);
        float ss2 = 0.f;
#pragma unroll
        for (int ni = 0; ni < 4; ++ni) ss2 += acc[mi][ni][r] * acc[mi][ni][r];
        ss2 += __shfl_xor(ss2, 1, 64);
        ss2 += __shfl_xor(ss2, 2, 64);
        ss2 += __shfl_xor(ss2, 4, 64);
        ss2 += __shfl_xor(ss2, 8, 64);
        float rr = rsqrtf(ss2 * (1.0f / 64.0f) + 1e-6f) * fscale;
        float c0 = ct[s * 32 + l16], c1 = ct[s * 32 + 16 + l16];
        float sn0 = st[s * 32 + l16], sn1 = st[s * 32 + 16 + l16];
#pragma unroll
        for (int ni = 0; ni < 4; ++ni) {
          float vn = acc[mi][ni][r] * rr * w0[ni];
          float vp = acc[mi][ni ^ 2][r] * rr * w0[ni ^ 2];
          float cs_ = (ni & 1) ? c1 : c0;
          float sn_ = (ni & 1) ? sn1 : sn0;
          float sg = (ni < 2) ? -1.0f : 1.0f;
          Ob[(bh * Ss + s) * HDd + ni * 16 + l16] = f2bf(vn * cs_ + sg * vp * sn_);
        }
      }
    }
  }
}

// -------- bf16 GEMM 128x64 tile (R7 verbatim; O-proj: 512 WGs) --------------
__global__ __launch_bounds__(256) void gemm_bt2(
    const unsigned short* __restrict__ A, const unsigned short* __restrict__ Bw,
    float* __restrict__ C, int M, int N, int K) {
  __shared__ __align__(16) unsigned short As[128 * 32];
  __shared__ __align__(16) unsigned short Bs[64 * 32];
  const int tid = threadIdx.x;
  const int lane = tid & 63;
  const int quad = lane >> 4;
  const int l16 = lane & 15;
  const int wave = tid >> 6;
  const int wm = (wave >> 1) * 64;
  const int wn = (wave & 1) * 32;
  const int tile_m = blockIdx.y * 128;
  const int tile_n = blockIdx.x * 64;

  const int off0 = tid * 16;
  const int off1 = 4096 + tid * 16;
  const int r0 = tid >> 2, r1 = r0 + 64;
  const int sch = (((tid & 3) ^ ((tid >> 3) & 3)) << 3);
  const int xg = ((quad ^ ((l16 >> 1) & 3)) << 3);

  const unsigned short* Ag0 = A + (size_t)(tile_m + r0) * K + sch;
  const unsigned short* Ag1 = A + (size_t)(tile_m + r1) * K + sch;
  const unsigned short* Bg0 = Bw + (size_t)(tile_n + r0) * K + sch;

  f32x4 zero = {0.f, 0.f, 0.f, 0.f};
  f32x4 acc[4][2];
#pragma unroll
  for (int mi = 0; mi < 4; ++mi)
#pragma unroll
    for (int ni = 0; ni < 2; ++ni) acc[mi][ni] = zero;

  for (int k0 = 0; k0 < K; k0 += 32) {
    gl_lds16(Ag0 + k0, (char*)As + off0);
    gl_lds16(Ag1 + k0, (char*)As + off1);
    gl_lds16(Bg0 + k0, (char*)Bs + off0);
    __syncthreads();
    bf16x8 af[4], bfv[2];
#pragma unroll
    for (int mi = 0; mi < 4; ++mi)
      af[mi] = *(const bf16x8*)&As[(wm + mi * 16 + l16) * 32 + xg];
#pragma unroll
    for (int ni = 0; ni < 2; ++ni)
      bfv[ni] = *(const bf16x8*)&Bs[(wn + ni * 16 + l16) * 32 + xg];
#pragma unroll
    for (int mi = 0; mi < 4; ++mi)
#pragma unroll
      for (int ni = 0; ni < 2; ++ni)
        acc[mi][ni] = __builtin_amdgcn_mfma_f32_16x16x32_bf16(
            af[mi], bfv[ni], acc[mi][ni], 0, 0, 0);
    __syncthreads();
  }

#pragma unroll
  for (int mi = 0; mi < 4; ++mi) {
#pragma unroll
    for (int ni = 0; ni < 2; ++ni) {
      int col = tile_n + wn + ni * 16 + l16;
#pragma unroll
      for (int r = 0; r < 4; ++r) {
        int row = tile_m + wm + mi * 16 + quad * 4 + r;
        C[(size_t)row * N + col] = acc[mi][ni][r];
      }
    }
  }
}

// -------- flash attention: S^T form, SW-pipelined K-loop, paired Q-tiles ----
// (R7 verbatim — best measured; R10's 512-thread shared-K/V variant was
// neutral: halved staging offset by 1-WG/CU barrier exposure)
__global__ __launch_bounds__(256) void flash(
    const unsigned short* __restrict__ Qb, const unsigned short* __restrict__ Kb,
    const unsigned short* __restrict__ Vt, const float* __restrict__ sink,
    unsigned short* __restrict__ Ob) {
  __shared__ __align__(16) unsigned short Qs[64 * 64];
  __shared__ __align__(16) unsigned short Ks[2][64 * 64];
  __shared__ __align__(16) unsigned short Vs[3][64 * 64];   // V^T tile [d][kv]
  __shared__ __align__(16) unsigned short Ps[4][16 * 72];   // [q][kv], +8 pad

  int tid = threadIdx.x, lane = tid & 63, wave = tid >> 6;
  int quad = lane >> 4, l16 = lane & 15;
  int bx = blockIdx.x;              // 0..15
  int h = blockIdx.y, b = blockIdx.z;

  const unsigned short* Qg = Qb + ((size_t)(b * Hh + h) * Ss) * HDd;
  const unsigned short* Kg = Kb + ((size_t)(b * Hh + h) * Ss) * HDd;
  const unsigned short* Vg = Vt + ((size_t)(b * Hh + h) * HDd) * Ss;

  int off0 = tid * 16, off1 = 4096 + tid * 16;
  int sr0 = tid >> 3, sr1 = sr0 + 32;
  int sch = ((tid & 7) ^ (sr0 & 7)) * 8;   // XOR-swizzled source chunk
  int x0 = ((quad ^ (l16 & 7)) * 8);       // swizzled read offset
  int x1 = x0 ^ 32;

  float sk = sink[h];
  f32x4 zero = {0.f, 0.f, 0.f, 0.f};

  bf16x8 ones;  // all-ones A-frag for l row-sum MFMA
  {
    u16x8 t;
#pragma unroll
    for (int i = 0; i < 8; ++i) t[i] = 0x3F80;  // bf16 1.0
    ones = *(bf16x8*)&t;
  }

#pragma unroll 1
  for (int pass = 0; pass < 2; ++pass) {
    int qt = pass ? bx : 31 - bx;     // long tile first
    int q0 = qt * 64;
    int myq = q0 + wave * 16 + l16;   // this lane's query

    __syncthreads();  // prior pass done with all LDS buffers
    gl_lds16(Qg + (size_t)(q0 + sr0) * 64 + sch, (char*)Qs + off0);
    gl_lds16(Qg + (size_t)(q0 + sr1) * 64 + sch, (char*)Qs + off1);
    gl_lds16(Kg + (size_t)sr0 * 64 + sch, (char*)Ks[0] + off0);
    gl_lds16(Kg + (size_t)sr1 * 64 + sch, (char*)Ks[0] + off1);
    gl_lds16(Vg + (size_t)sr0 * Ss + sch, (char*)Vs[0] + off0);
    gl_lds16(Vg + (size_t)sr1 * Ss + sch, (char*)Vs[0] + off1);

    f32x4 Oacc[4], lacc = zero;
#pragma unroll
    for (int ni = 0; ni < 4; ++ni) Oacc[ni] = zero;

    __syncthreads();  // Q, K0, V0 staged
    bf16x8 aq0 = *(const bf16x8*)&Qs[(wave * 16 + l16) * 64 + x0];
    bf16x8 aq1 = *(const bf16x8*)&Qs[(wave * 16 + l16) * 64 + x1];
    if (qt >= 1) {  // prefetch tile 1
      gl_lds16(Kg + (size_t)(64 + sr0) * 64 + sch, (char*)Ks[1] + off0);
      gl_lds16(Kg + (size_t)(64 + sr1) * 64 + sch, (char*)Ks[1] + off1);
      gl_lds16(Vg + (size_t)sr0 * Ss + 64 + sch, (char*)Vs[1] + off0);
      gl_lds16(Vg + (size_t)sr1 * Ss + 64 + sch, (char*)Vs[1] + off1);
    }

    // QK for kt=0
    f32x4 sc[4];
#pragma unroll
    for (int ni = 0; ni < 4; ++ni) {
      bf16x8 bk0 = *(const bf16x8*)&Ks[0][(ni * 16 + l16) * 64 + x0];
      bf16x8 bk1 = *(const bf16x8*)&Ks[0][(ni * 16 + l16) * 64 + x1];
      sc[ni] = __builtin_amdgcn_mfma_f32_16x16x32_bf16(bk0, aq0, zero, 0, 0, 0);
      sc[ni] = __builtin_amdgcn_mfma_f32_16x16x32_bf16(bk1, aq1, sc[ni], 0, 0, 0);
    }
    if (qt == 0) {
#pragma unroll
      for (int ni = 0; ni < 4; ++ni)
#pragma unroll
        for (int r = 0; r < 4; ++r)
          if (ni * 16 + quad * 4 + r > myq - q0) sc[ni][r] = -1.0e38f;
    }

    for (int kt = 0; kt <= qt; ++kt) {
      bool last = (kt == qt);
      if (!last) __syncthreads();  // K/V[kt+1] staged (drains prefetch)
      if (kt + 2 <= qt) {          // prefetch kt+2 (K dbuf, V tbuf)
        int vb = (kt + 2) % 3, kb = kt & 1;
        gl_lds16(Kg + (size_t)((kt + 2) * 64 + sr0) * 64 + sch, (char*)Ks[kb] + off0);
        gl_lds16(Kg + (size_t)((kt + 2) * 64 + sr1) * 64 + sch, (char*)Ks[kb] + off1);
        gl_lds16(Vg + (size_t)sr0 * Ss + (kt + 2) * 64 + sch, (char*)Vs[vb] + off0);
        gl_lds16(Vg + (size_t)sr1 * Ss + (kt + 2) * 64 + sch, (char*)Vs[vb] + off1);
      }

      // p = exp2(sc[kt]); pack & write P (VALU overlaps next K-frag latency)
#pragma unroll
      for (int ni = 0; ni < 4; ++ni) {
        ushort4 pk;
        pk.x = f2bf_fast(exp2f(sc[ni][0]));
        pk.y = f2bf_fast(exp2f(sc[ni][1]));
        pk.z = f2bf_fast(exp2f(sc[ni][2]));
        pk.w = f2bf_fast(exp2f(sc[ni][3]));
        *(ushort4*)&Ps[wave][l16 * 72 + ni * 16 + quad * 4] = pk;
      }

      // QK for kt+1 (pipelined above PV[kt])
      f32x4 scn[4];
      if (!last) {
        const unsigned short* Kt = Ks[(kt + 1) & 1];
#pragma unroll
        for (int ni = 0; ni < 4; ++ni) {
          bf16x8 bk0 = *(const bf16x8*)&Kt[(ni * 16 + l16) * 64 + x0];
          bf16x8 bk1 = *(const bf16x8*)&Kt[(ni * 16 + l16) * 64 + x1];
          scn[ni] = __builtin_amdgcn_mfma_f32_16x16x32_bf16(bk0, aq0, zero, 0, 0, 0);
          scn[ni] = __builtin_amdgcn_mfma_f32_16x16x32_bf16(bk1, aq1, scn[ni], 0, 0, 0);
        }
        if (kt + 1 == qt) {  // diagonal mask for next tile
#pragma unroll
          for (int ni = 0; ni < 4; ++ni)
#pragma unroll
            for (int r = 0; r < 4; ++r)
              if ((kt + 1) * 64 + ni * 16 + quad * 4 + r > myq) scn[ni][r] = -1.0e38f;
        }
      }

      asm volatile("s_waitcnt lgkmcnt(0)" ::: "memory");  // P visible in-wave
      bf16x8 ap0 = *(const bf16x8*)&Ps[wave][l16 * 72 + quad * 8];
      bf16x8 ap1 = *(const bf16x8*)&Ps[wave][l16 * 72 + 32 + quad * 8];

      // O^T[d][q] += V^T·P^T ; l row-sum via ones-frag MFMA
      const unsigned short* Vtile = Vs[kt % 3];
#pragma unroll
      for (int ni = 0; ni < 4; ++ni) {
        bf16x8 bv0 = *(const bf16x8*)&Vtile[(ni * 16 + l16) * 64 + x0];
        bf16x8 bv1 = *(const bf16x8*)&Vtile[(ni * 16 + l16) * 64 + x1];
        Oacc[ni] = __builtin_amdgcn_mfma_f32_16x16x32_bf16(bv0, ap0, Oacc[ni], 0, 0, 0);
        Oacc[ni] = __builtin_amdgcn_mfma_f32_16x16x32_bf16(bv1, ap1, Oacc[ni], 0, 0, 0);
      }
      lacc = __builtin_amdgcn_mfma_f32_16x16x32_bf16(ones, ap0, lacc, 0, 0, 0);
      lacc = __builtin_amdgcn_mfma_f32_16x16x32_bf16(ones, ap1, lacc, 0, 0, 0);

      if (!last) {
#pragma unroll
        for (int ni = 0; ni < 4; ++ni) sc[ni] = scn[ni];
      }
    }

    // epilogue: every lane already holds l(q=myq) in lacc[0]
    float inv = 1.0f / (lacc[0] + exp2f(sk * 1.44269504f));
#pragma unroll
    for (int ni = 0; ni < 4; ++ni) {
      ushort4 ov;
      ov.x = f2bf(Oacc[ni][0] * inv);
      ov.y = f2bf(Oacc[ni][1] * inv);
      ov.z = f2bf(Oacc[ni][2] * inv);
      ov.w = f2bf(Oacc[ni][3] * inv);
      *(ushort4*)&Ob[((size_t)b * Ss + myq) * Dd + h * 64 + ni * 16 + quad * 4] = ov;
    }
  }
}

extern "C" void kernel_launch(void* const* d_in, const int* in_sizes, int n_in,
                              void* d_out, int out_size, void* d_ws, size_t ws_size,
                              hipStream_t stream) {
  const float* x  = (const float*)d_in[0];
  const float* wq = (const float*)d_in[1];
  const float* wk = (const float*)d_in[2];
  const float* wv = (const float*)d_in[3];
  const float* wo = (const float*)d_in[4];
  const float* qw = (const float*)d_in[5];
  const float* kw = (const float*)d_in[6];
  const float* sk = (const float*)d_in[7];

  char* ws = (char*)d_ws;
  const size_t MB = 1ull << 20;
  unsigned short* xb    = (unsigned short*)(ws + 0);       // 8 MB (dead after gemm_qkv)
  unsigned short* attnb = (unsigned short*)(ws + 0);       // 8 MB (after flash)
  unsigned short* wqkvb = (unsigned short*)(ws + 8 * MB);  // 6 MB
  unsigned short* wob   = (unsigned short*)(ws + 14 * MB); // 2 MB
  float*          ct    = (float*)(ws + 16 * MB);          // 256 KB
  float*          st    = (float*)(ws + 17 * MB);          // 256 KB
  unsigned short* Qb    = (unsigned short*)(ws + 40 * MB); // 8 MB
  unsigned short* Kb    = (unsigned short*)(ws + 48 * MB); // 8 MB
  unsigned short* Vt    = (unsigned short*)(ws + 56 * MB); // 8 MB

  cast_all<<<8448, 256, 0, stream>>>(
      (const float4*)x, (const float4*)wq, (const float4*)wk, (const float4*)wv,
      (const float4*)wo, (ushort4*)xb, (ushort4*)wqkvb, (ushort4*)wob, ct, st);
  gemm_qkv<<<dim3(24, 32), 256, 0, stream>>>(xb, wqkvb, qw, kw, ct, st, Qb, Kb, Vt);
  flash<<<dim3(16, Hh, Bb), 256, 0, stream>>>(Qb, Kb, Vt, sk, attnb);
  gemm_bt2<<<dim3(16, 32), 256, 0, stream>>>(attnb, wob, (float*)d_out, BS, Dd, Dd);
}